// Round 3
// baseline (6070.446 us; speedup 1.0000x reference)
//
#include <hip/hip_runtime.h>
#include <math.h>
#include <float.h>
#include <limits.h>

#define BB 64        // batch (== wavefront size)
#define HID 768
#define VOCAB 30000
#define TSTEPS 32
#define CPW 8                      // logit cols per wave
#define NWAVE (VOCAB / CPW)        // 3750
#define NBLK ((NWAVE + 3) / 4)     // 938

// ---------------------------------------------------------------------------
// Closed head stage 1: hid[b][r] = relu(feat[b] . c1W[r] + c1b[r]).
// ---------------------------------------------------------------------------
__global__ __launch_bounds__(256) void kc1(
    const float* __restrict__ feat, const float* __restrict__ c1W,
    const float* __restrict__ c1b, float* __restrict__ hid_ws)
{
    const int q = blockIdx.x, b = blockIdx.y;
    const int wave = threadIdx.x >> 6, lane = threadIdx.x & 63;
    float4 fr[3];
    const float4* frow = (const float4*)(feat + (size_t)b * HID);
    #pragma unroll
    for (int j = 0; j < 3; j++) fr[j] = frow[lane + 64 * j];

    #pragma unroll 2
    for (int rr = 0; rr < 32; rr++) {
        const int r = q * 128 + wave * 32 + rr;
        const float4* w = (const float4*)(c1W + (size_t)r * HID);
        float s = 0.f;
        #pragma unroll
        for (int j = 0; j < 3; j++) {
            float4 wv = w[lane + 64 * j];
            s += fr[j].x * wv.x + fr[j].y * wv.y + fr[j].z * wv.z + fr[j].w * wv.w;
        }
        #pragma unroll
        for (int o = 32; o; o >>= 1) s += __shfl_xor(s, o, 64);
        if (lane == 0) hid_ws[b * 512 + r] = fmaxf(s + c1b[r], 0.f);
    }
}

// Closed head stage 2.
__global__ __launch_bounds__(256) void kc2(
    const float* __restrict__ hid_ws, const float* __restrict__ c2W,
    const float* __restrict__ c2b, float* __restrict__ out)
{
    const int b = blockIdx.x, tid = threadIdx.x;
    __shared__ float red[2][256];
    float s0 = 0.f, s1 = 0.f;
    for (int r = tid; r < 512; r += 256) {
        float hv = hid_ws[b * 512 + r];
        s0 += hv * c2W[r];
        s1 += hv * c2W[512 + r];
    }
    red[0][tid] = s0; red[1][tid] = s1;
    __syncthreads();
    for (int st = 128; st; st >>= 1) {
        if (tid < st) { red[0][tid] += red[0][tid + st]; red[1][tid] += red[1][tid + st]; }
        __syncthreads();
    }
    if (tid == 0) {
        out[b * 2 + 0] = red[0][0] + c2b[0];
        out[b * 2 + 1] = red[1][0] + c2b[1];
    }
}

// ---------------------------------------------------------------------------
// Prep: hA[k][b] = feat[b][k] (h0 = feat, transposed); xT[k][b] = emb[0][k].
// ---------------------------------------------------------------------------
__global__ __launch_bounds__(256) void kprep(
    const float* __restrict__ feat, const float* __restrict__ emb,
    float* __restrict__ hA, float* __restrict__ xT)
{
    int idx = blockIdx.x * 256 + threadIdx.x;   // < 768*64
    int k = idx >> 6, b = idx & 63;
    hA[idx] = feat[b * HID + k];
    xT[idx] = emb[k];
}

// ---------------------------------------------------------------------------
// Fused gates GEMM + LSTM cell. Wave = one hidden index j (0..767); lane =
// batch row m. Gate weights are wave-uniform -> scalar loads; x/h come from
// transposed buffers (coalesced dword per lane). Barrier-free.
// ---------------------------------------------------------------------------
__global__ __launch_bounds__(256) void kgate(
    int step, const float* __restrict__ xT, const float* __restrict__ hT_in,
    const float* __restrict__ W_ih, const float* __restrict__ W_hh,
    const float* __restrict__ b_ih, const float* __restrict__ b_hh,
    float* __restrict__ cT, float* __restrict__ hT_out)
{
    const int lane = threadIdx.x & 63;
    const int j = __builtin_amdgcn_readfirstlane((blockIdx.x << 2) | (threadIdx.x >> 6));

    float acc[4];
    #pragma unroll
    for (int g = 0; g < 4; g++) acc[g] = b_ih[g * HID + j] + b_hh[g * HID + j];

    // x @ W_ih.T contribution
    for (int k0 = 0; k0 < HID; k0 += 16) {
        float xv[16];
        #pragma unroll
        for (int kk = 0; kk < 16; kk++) xv[kk] = xT[(k0 + kk) * 64 + lane];
        #pragma unroll
        for (int g = 0; g < 4; g++) {
            const float* w = W_ih + (size_t)(g * HID + j) * HID + k0;
            #pragma unroll
            for (int kk = 0; kk < 16; kk++) acc[g] = fmaf(xv[kk], w[kk], acc[g]);
        }
    }
    // h @ W_hh.T contribution
    for (int k0 = 0; k0 < HID; k0 += 16) {
        float hv[16];
        #pragma unroll
        for (int kk = 0; kk < 16; kk++) hv[kk] = hT_in[(k0 + kk) * 64 + lane];
        #pragma unroll
        for (int g = 0; g < 4; g++) {
            const float* w = W_hh + (size_t)(g * HID + j) * HID + k0;
            #pragma unroll
            for (int kk = 0; kk < 16; kk++) acc[g] = fmaf(hv[kk], w[kk], acc[g]);
        }
    }

    float cprev = (step == 0) ? 0.f : cT[j * 64 + lane];
    float ig = 1.f / (1.f + expf(-acc[0]));
    float fg = 1.f / (1.f + expf(-acc[1]));
    float gg = tanhf(acc[2]);
    float og = 1.f / (1.f + expf(-acc[3]));
    float cn = fg * cprev + ig * gg;
    float hn = og * tanhf(cn);
    cT[j * 64 + lane] = cn;
    hT_out[j * 64 + lane] = hn;
}

// ---------------------------------------------------------------------------
// Logits GEMV-batch + per-wave argmax. Wave wid owns cols [wid*8, wid*8+8);
// lane = batch row m. out_W rows are wave-uniform -> scalar pipe. No LDS.
// Per-logit FMA chain over k ascending (bit-identical to prior rounds).
// ---------------------------------------------------------------------------
__global__ __launch_bounds__(256) void klog(
    const float* __restrict__ hT, const float* __restrict__ outW,
    const float* __restrict__ outb, float* __restrict__ pval, int* __restrict__ pidx)
{
    const int lane = threadIdx.x & 63;
    const int wid = __builtin_amdgcn_readfirstlane((blockIdx.x << 2) | (threadIdx.x >> 6));
    if (wid >= NWAVE) return;
    const int n0 = wid * CPW;

    float acc[CPW] = {};
    float hv[16], hn[16];
    #pragma unroll
    for (int kk = 0; kk < 16; kk++) hv[kk] = hT[kk * 64 + lane];

    for (int k0 = 0; k0 < HID; k0 += 16) {
        if (k0 + 16 < HID) {
            #pragma unroll
            for (int kk = 0; kk < 16; kk++) hn[kk] = hT[(k0 + 16 + kk) * 64 + lane];
        }
        #pragma unroll
        for (int c = 0; c < CPW; c++) {
            const float* w = outW + (size_t)(n0 + c) * HID + k0;
            #pragma unroll
            for (int kk = 0; kk < 16; kk++) acc[c] = fmaf(hv[kk], w[kk], acc[c]);
        }
        if (k0 + 16 < HID) {
            #pragma unroll
            for (int kk = 0; kk < 16; kk++) hv[kk] = hn[kk];
        }
    }

    // per-lane argmax over this wave's cols (ascending -> first occurrence)
    float bv = -FLT_MAX; int bi = INT_MAX;
    #pragma unroll
    for (int c = 0; c < CPW; c++) {
        float v = acc[c] + outb[n0 + c];
        if (v > bv) { bv = v; bi = n0 + c; }
    }
    pval[lane * NWAVE + wid] = bv;
    pidx[lane * NWAVE + wid] = bi;
}

// ---------------------------------------------------------------------------
// Finalize token for batch row b; gather xT = emb[tok]^T for the next step.
// ---------------------------------------------------------------------------
__global__ __launch_bounds__(256) void kfin(
    int step, const float* __restrict__ pval, const int* __restrict__ pidx,
    const float* __restrict__ emb, float* __restrict__ xT, float* __restrict__ gen)
{
    const int b = blockIdx.x, tid = threadIdx.x;
    __shared__ float sv[256];
    __shared__ int   si[256];
    __shared__ int   stok;
    float bv = -FLT_MAX; int bi = INT_MAX;
    for (int p = tid; p < NWAVE; p += 256) {
        float v = pval[b * NWAVE + p]; int ix = pidx[b * NWAVE + p];
        if (v > bv || (v == bv && ix < bi)) { bv = v; bi = ix; }
    }
    sv[tid] = bv; si[tid] = bi;
    __syncthreads();
    for (int st = 128; st; st >>= 1) {
        if (tid < st) {
            float v = sv[tid + st]; int ix = si[tid + st];
            if (v > sv[tid] || (v == sv[tid] && ix < si[tid])) { sv[tid] = v; si[tid] = ix; }
        }
        __syncthreads();
    }
    if (tid == 0) {
        stok = si[0];
        gen[b * TSTEPS + step] = (float)si[0];
    }
    __syncthreads();
    const int tok = stok;
    for (int k = tid; k < HID; k += 256)
        xT[k * 64 + b] = emb[(size_t)tok * HID + k];
}

// ---------------------------------------------------------------------------
extern "C" void kernel_launch(void* const* d_in, const int* in_sizes, int n_in,
                              void* d_out, int out_size, void* d_ws, size_t ws_size,
                              hipStream_t stream)
{
    const float* feat = (const float*)d_in[0];
    const float* emb  = (const float*)d_in[1];
    const float* W_ih = (const float*)d_in[2];
    const float* W_hh = (const float*)d_in[3];
    const float* b_ih = (const float*)d_in[4];
    const float* b_hh = (const float*)d_in[5];
    const float* outW = (const float*)d_in[6];
    const float* outb = (const float*)d_in[7];
    const float* c1W  = (const float*)d_in[8];
    const float* c1b  = (const float*)d_in[9];
    const float* c2W  = (const float*)d_in[10];
    const float* c2b  = (const float*)d_in[11];
    (void)in_sizes; (void)n_in; (void)out_size; (void)ws_size;

    float* out = (float*)d_out;
    float* gen = out + BB * 2;                  // generated (64x32), as floats

    float* ws     = (float*)d_ws;
    float* hA     = ws;                         // 768*64
    float* hB     = hA + HID * 64;              // 768*64
    float* cT     = hB + HID * 64;              // 768*64
    float* xT     = cT + HID * 64;              // 768*64
    float* pval   = xT + HID * 64;              // 64*3750
    int*   pidx   = (int*)(pval + BB * NWAVE);  // 64*3750
    float* hid_ws = (float*)(pidx + BB * NWAVE);// 64*512

    kc1<<<dim3(4, BB), 256, 0, stream>>>(feat, c1W, c1b, hid_ws);
    kc2<<<BB, 256, 0, stream>>>(hid_ws, c2W, c2b, out);
    kprep<<<dim3(HID * 64 / 256), 256, 0, stream>>>(feat, emb, hA, xT);

    for (int t = 0; t < TSTEPS; t++) {
        const float* h_in = (t & 1) ? hB : hA;
        float*       h_out = (t & 1) ? hA : hB;
        kgate<<<dim3(192), 256, 0, stream>>>(t, xT, h_in, W_ih, W_hh, b_ih, b_hh, cT, h_out);
        klog<<<dim3(NBLK), 256, 0, stream>>>(h_out, outW, outb, pval, pidx);
        kfin<<<BB, 256, 0, stream>>>(t, pval, pidx, emb, xT, gen);
    }
}